// Round 3
// baseline (128.232 us; speedup 1.0000x reference)
//
#include <hip/hip_runtime.h>
#include <hip/hip_bf16.h>

// B=1, T=2048, H=16, D=64, G=16, HKV=1, BS=64, S=16, NB=32.
// R3: split-S flash-decode. One workgroup per token; each of the 4 waves
// handles 4 of the 16 selected blocks with mfma_f32_16x16x32_f16
// (M dim = all 16 heads), then partials merge through LDS.
#define T_    2048
#define H_    16
#define D_    64
#define S_    16
#define BS_   64
#define CEXP  0.1803368801111204f   // SCALE * log2(e)

typedef _Float16 f16x8 __attribute__((ext_vector_type(8)));
typedef _Float16 f16x4 __attribute__((ext_vector_type(4)));
typedef float    f32x4 __attribute__((ext_vector_type(4)));

#define MFMA16(a, b, c) __builtin_amdgcn_mfma_f32_16x16x32_f16((a), (b), (c), 0, 0, 0)

// ---- prepass: K -> f16 [token][64]; V -> f16 transposed [dim][2048].
// Coalesced on both sides via an LDS tile transpose (64 tokens per wg).
__global__ __launch_bounds__(256) void nsa_prep(
    const float* __restrict__ K, const float* __restrict__ V,
    _Float16* __restrict__ Kf, _Float16* __restrict__ Vt)
{
    __shared__ _Float16 tile[64][72];   // [dim][token], padded
    const int tb  = blockIdx.x;         // token tile 0..31
    const int tid = threadIdx.x;
    const float4* K4 = (const float4*)(K + (size_t)tb * 4096);
    const float4* V4 = (const float4*)(V + (size_t)tb * 4096);
#pragma unroll
    for (int u = 0; u < 4; ++u) {
        const int f = u * 256 + tid;            // float4 idx 0..1023 (lane-contig)
        const float4 kq = K4[f];
        *(f16x4*)(Kf + (size_t)tb * 4096 + f * 4) =
            (f16x4){(_Float16)kq.x, (_Float16)kq.y, (_Float16)kq.z, (_Float16)kq.w};
        const float4 vq = V4[f];
        const int t = f >> 4;                   // token in tile
        const int d = (f & 15) << 2;            // dim
        tile[d + 0][t] = (_Float16)vq.x;
        tile[d + 1][t] = (_Float16)vq.y;
        tile[d + 2][t] = (_Float16)vq.z;
        tile[d + 3][t] = (_Float16)vq.w;
    }
    __syncthreads();
#pragma unroll
    for (int u = 0; u < 2; ++u) {
        const int idx = u * 256 + tid;          // 0..511
        const int d  = idx >> 3;
        const int tc = (idx & 7) << 3;
        *(f16x8*)(Vt + (size_t)d * T_ + tb * 64 + tc) = *(const f16x8*)&tile[d][tc];
    }
}

__global__ __launch_bounds__(256) void nsa_mfma(
    const float* __restrict__ Q, const int* __restrict__ BI,
    const _Float16* __restrict__ Kf, const _Float16* __restrict__ Vt,
    float* __restrict__ Out)
{
    // Union: during the s-loop, per-wave P transpose buffers (4 x 16 x 72 f16
    // = 9216 B); after the post-loop barrier, merge buffers ov[4][16][68] f32
    // + ml[4][16][2] f32 (17920 B). Stride 68 floats => partial writes are
    // 2-way bank aliased (free).
    __shared__ float smem[4480];

    const int tid  = threadIdx.x;
    const int wv   = tid >> 6;
    const int lane = tid & 63;
    const int t    = blockIdx.x;
    const int g    = lane >> 4;     // quad 0..3
    const int c    = lane & 15;     // col / m-index

    _Float16* pbuf = (_Float16*)smem + wv * (16 * 72);

    // ---- Q A-fragments: A[m=head=c][k = ks*32 + g*8 + j] ----
    f16x8 qa[2];
    {
        const float* qp = Q + ((size_t)t * H_ + c) * D_ + g * 8;
#pragma unroll
        for (int ks = 0; ks < 2; ++ks) {
            const float4 x = *(const float4*)(qp + ks * 32);
            const float4 y = *(const float4*)(qp + ks * 32 + 4);
            qa[ks] = (f16x8){(_Float16)x.x, (_Float16)x.y, (_Float16)x.z, (_Float16)x.w,
                             (_Float16)y.x, (_Float16)y.y, (_Float16)y.z, (_Float16)y.w};
        }
    }

    // ones-column B fragment for the l (row-sum) accumulator
    const _Float16 ov16 = (c == 0) ? (_Float16)1.0f : (_Float16)0.0f;
    const f16x8 lb = (f16x8){ov16, ov16, ov16, ov16, ov16, ov16, ov16, ov16};

    f32x4 o[4], lt;
#pragma unroll
    for (int nt = 0; nt < 4; ++nt) o[nt] = (f32x4){0.f, 0.f, 0.f, 0.f};
    lt = (f32x4){0.f, 0.f, 0.f, 0.f};
    float mrow[4] = {-1e30f, -1e30f, -1e30f, -1e30f};

    for (int si = 0; si < 4; ++si) {
        const int blk = BI[t * S_ + wv * 4 + si];   // wave-uniform -> scalar load

        // ---- B-fragments straight from global (f16, L1/L2-hit) ----
        f16x8 kb[4][2], vb[4][2];
        {
            const _Float16* kp = Kf + ((blk * BS_ + c) * D_) + g * 8;
            const _Float16* vp = Vt + (size_t)c * T_ + blk * BS_ + g * 8;
#pragma unroll
            for (int nt = 0; nt < 4; ++nt) {
#pragma unroll
                for (int ks = 0; ks < 2; ++ks) {
                    kb[nt][ks] = *(const f16x8*)(kp + nt * 16 * D_ + ks * 32);
                    vb[nt][ks] = *(const f16x8*)(vp + (size_t)nt * 16 * T_ + ks * 32);
                }
            }
        }

        // ---- QK^T: S[head=4g+r][key=nt*16+c] in C-layout ----
        f32x4 sc[4];
#pragma unroll
        for (int nt = 0; nt < 4; ++nt) {
            sc[nt] = MFMA16(qa[0], kb[nt][0], ((f32x4){0.f, 0.f, 0.f, 0.f}));
            sc[nt] = MFMA16(qa[1], kb[nt][1], sc[nt]);
        }

        bool valid[4];
#pragma unroll
        for (int nt = 0; nt < 4; ++nt) valid[nt] = (blk * BS_ + nt * 16 + c) <= t;

        // ---- online softmax: 16-lane row reductions within the quad ----
        float alpha[4];
#pragma unroll
        for (int r = 0; r < 4; ++r) {
            float mx = -1e30f;
#pragma unroll
            for (int nt = 0; nt < 4; ++nt) mx = fmaxf(mx, valid[nt] ? sc[nt][r] : -1e30f);
            mx = fmaxf(mx, __shfl_xor(mx, 1));
            mx = fmaxf(mx, __shfl_xor(mx, 2));
            mx = fmaxf(mx, __shfl_xor(mx, 4));
            mx = fmaxf(mx, __shfl_xor(mx, 8));
            const float mn = fmaxf(mrow[r], mx);
            alpha[r] = exp2f((mrow[r] - mn) * CEXP);
            mrow[r] = mn;
        }

        // ---- p to LDS in [head][key] layout (wave-private, same-wave RAW) ----
#pragma unroll
        for (int nt = 0; nt < 4; ++nt) {
#pragma unroll
            for (int r = 0; r < 4; ++r) {
                const float p = valid[nt] ? exp2f((sc[nt][r] - mrow[r]) * CEXP) : 0.f;
                pbuf[(4 * g + r) * 72 + nt * 16 + c] = (_Float16)p;
            }
        }

#pragma unroll
        for (int nt = 0; nt < 4; ++nt) {
#pragma unroll
            for (int r = 0; r < 4; ++r) o[nt][r] *= alpha[r];
        }
#pragma unroll
        for (int r = 0; r < 4; ++r) lt[r] *= alpha[r];

        // ---- read P as A-fragments ----
        f16x8 pa[2];
#pragma unroll
        for (int ks = 0; ks < 2; ++ks)
            pa[ks] = *(const f16x8*)(pbuf + c * 72 + ks * 32 + g * 8);

        // ---- PV (+ l via ones column) ----
#pragma unroll
        for (int nt = 0; nt < 4; ++nt) {
            o[nt] = MFMA16(pa[0], vb[nt][0], o[nt]);
            o[nt] = MFMA16(pa[1], vb[nt][1], o[nt]);
        }
        lt = MFMA16(pa[0], lb, lt);
        lt = MFMA16(pa[1], lb, lt);
    }

    // ---- publish partials (overlays pbuf region; barrier first) ----
    __syncthreads();
    float* ovp = smem;                // [w][h][68]
    float* mlp = smem + 4 * 16 * 68;  // [w][h][2]
    if (c == 0) {
#pragma unroll
        for (int r = 0; r < 4; ++r) {
            mlp[(wv * 16 + 4 * g + r) * 2 + 0] = mrow[r];
            mlp[(wv * 16 + 4 * g + r) * 2 + 1] = lt[r];
        }
    }
#pragma unroll
    for (int nt = 0; nt < 4; ++nt) {
#pragma unroll
        for (int r = 0; r < 4; ++r)
            ovp[(wv * 16 + 4 * g + r) * 68 + nt * 16 + c] = o[nt][r];
    }
    __syncthreads();

    // ---- merge: wave wv handles heads 4wv..4wv+3, lane = output dim ----
    float* outp = Out + (size_t)t * (H_ * D_);
#pragma unroll
    for (int q = 0; q < 4; ++q) {
        const int h = wv * 4 + q;
        const float m0 = mlp[(0 * 16 + h) * 2], l0 = mlp[(0 * 16 + h) * 2 + 1];
        const float m1 = mlp[(1 * 16 + h) * 2], l1 = mlp[(1 * 16 + h) * 2 + 1];
        const float m2 = mlp[(2 * 16 + h) * 2], l2 = mlp[(2 * 16 + h) * 2 + 1];
        const float m3 = mlp[(3 * 16 + h) * 2], l3 = mlp[(3 * 16 + h) * 2 + 1];
        const float M  = fmaxf(fmaxf(m0, m1), fmaxf(m2, m3));
        const float a0 = exp2f((m0 - M) * CEXP);
        const float a1 = exp2f((m1 - M) * CEXP);
        const float a2 = exp2f((m2 - M) * CEXP);
        const float a3 = exp2f((m3 - M) * CEXP);
        const float L  = a0 * l0 + a1 * l1 + a2 * l2 + a3 * l3;
        const float acc = a0 * ovp[(0 * 16 + h) * 68 + lane]
                        + a1 * ovp[(1 * 16 + h) * 68 + lane]
                        + a2 * ovp[(2 * 16 + h) * 68 + lane]
                        + a3 * ovp[(3 * 16 + h) * 68 + lane];
        outp[h * D_ + lane] = acc / L;
    }
}

extern "C" void kernel_launch(void* const* d_in, const int* in_sizes, int n_in,
                              void* d_out, int out_size, void* d_ws, size_t ws_size,
                              hipStream_t stream) {
    const float* Q  = (const float*)d_in[0];
    const float* K  = (const float*)d_in[1];
    const float* V  = (const float*)d_in[2];
    const int*   BI = (const int*)d_in[3];
    float*       Out = (float*)d_out;

    _Float16* Kf = (_Float16*)d_ws;                 // 2048*64 f16 = 256 KB
    _Float16* Vt = Kf + (size_t)T_ * D_;            // 64*2048 f16 = 256 KB

    nsa_prep<<<dim3(T_ / 64), dim3(256), 0, stream>>>(K, V, Kf, Vt);
    nsa_mfma<<<dim3(T_), dim3(256), 0, stream>>>(Q, BI, Kf, Vt, Out);
}